// Round 9
// baseline (7954.252 us; speedup 1.0000x reference)
//
#include <hip/hip_runtime.h>
#include <math.h>

#define N_U 7
#define N_E 14
#define N_DET 16
#define N_FB 3
#define N_SV 256
#define N_PV 32
#define N_PAIR 196   // 14*14

// ---- dynamic-LDS layout (floats), 2 elements per block ----
#define F_SV   3584   // 14*256
#define F_PV   6272   // 196*32
#define F_MU   256
#define F_PUPD 448    // 14*32
#define F_SU   1568   // union: max(sblk0 448 + pin 784 = 1232, orb 32*49 = 1568)
#define OFF_SV   0
#define OFF_PV   (OFF_SV + 2*F_SV)      // 7168
#define OFF_MU   (OFF_PV + 2*F_PV)      // 19712
#define OFF_MD   (OFF_MU + 2*F_MU)      // 20224
#define OFF_PU   (OFF_MD + 2*F_MU)      // 20736
#define OFF_PD   (OFF_PU + 2*F_PUPD)    // 21632
#define OFF_SU   (OFF_PD + 2*F_PUPD)    // 22528
#define OFF_ENV  (OFF_SU + 2*F_SU)      // 25664 (16 floats/half)
#define OFF_RB   (OFF_ENV + 2*16)       // 25696 (48 floats/half)
#define OFF_DSG  (OFF_RB + 2*48)        // 25792 (32/half)
#define OFF_DLD  (OFF_DSG + 2*32)       // 25856 (32/half)
#define LDS_FLOATS (OFF_DLD + 2*32)     // 25920
#define LDS_BYTES  (LDS_FLOATS * 4)     // 103680

__device__ __forceinline__ float tanh_fast(float x) {
    float e = __expf(2.0f * x);
    return 1.0f - __fdividef(2.0f, e + 1.0f);
}

extern "C" __global__ void __launch_bounds__(512, 1)
ansatz_kernel(const float* __restrict__ r_g,
              const float* __restrict__ s_w0, const float* __restrict__ s_b0,
              const float* __restrict__ s_w,  const float* __restrict__ s_b,
              const float* __restrict__ p_w0, const float* __restrict__ p_b0,
              const float* __restrict__ p_w,  const float* __restrict__ p_b,
              const float* __restrict__ va_w, const float* __restrict__ va_b,
              const float* __restrict__ wu_w, const float* __restrict__ wu_b,
              const float* __restrict__ wd_w, const float* __restrict__ wd_b,
              const float* __restrict__ wf_w, float* __restrict__ out)
{
    extern __shared__ float lds[];

    // XCD-aware bijective swizzle (gridDim.x = 2048, % 8 == 0)
    const int bid = blockIdx.x;
    const int nwg = gridDim.x;
    const int bsw = ((nwg & 7) == 0) ? ((bid & 7) * (nwg >> 3) + (bid >> 3)) : bid;
    const int t  = threadIdx.x;
    const int h  = t >> 8;          // element half: 0 or 1
    const int tl = t & 255;         // local thread id within half
    const int b2 = 2 * bsw + h;     // batch element

    float* svp  = lds + OFF_SV  + h * F_SV;    // [14][256]
    float* pvp  = lds + OFF_PV  + h * F_PV;    // [196][32]
    float* mu   = lds + OFF_MU  + h * F_MU;
    float* md   = lds + OFF_MD  + h * F_MU;
    float* pu   = lds + OFF_PU  + h * F_PUPD;  // [14][32]
    float* pd   = lds + OFF_PD  + h * F_PUPD;
    float* sb   = lds + OFF_SU  + h * F_SU;    // union: sblk0[14][32] @0, pin[196][4] @448; orb[32][49] @0
    float* env  = lds + OFF_ENV + h * 16;
    float* rb   = lds + OFF_RB  + h * 48;
    float* dsgp = lds + OFF_DSG + h * 32;
    float* dldp = lds + OFF_DLD + h * 32;

    // ---- load r ----
    if (tl < N_E * 3) rb[tl] = r_g[b2 * N_E * 3 + tl];
    __syncthreads();

    // ---- raw features ----
    if (tl < N_E) {
        float rx = rb[tl * 3], ry = rb[tl * 3 + 1], rz = rb[tl * 3 + 2];
        float l0 = sqrtf(rx * rx + ry * ry + rz * rz);
        float z1 = rz - 1.4f;
        float l1 = sqrtf(rx * rx + ry * ry + z1 * z1);
        float* s0 = sb + tl * 32;
        s0[0] = rx; s0[1] = ry; s0[2] = rz; s0[3] = l0;
        s0[4] = rx; s0[5] = ry; s0[6] = z1; s0[7] = l1;
        env[tl] = __expf(-l0) + __expf(-l1);
    }
    if (tl < N_PAIR) {
        int i = tl / N_E, j = tl % N_E;
        float dx = rb[j * 3 + 0] - rb[i * 3 + 0];
        float dy = rb[j * 3 + 1] - rb[i * 3 + 1];
        float dz = rb[j * 3 + 2] - rb[i * 3 + 2];
        float ee = (i == j) ? 1.0f : 0.0f;
        float lx = dx + ee, ly = dy + ee, lz = dz + ee;
        float len = sqrtf(lx * lx + ly * ly + lz * lz);
        float* pn = sb + 448 + tl * 4;
        pn[0] = dx; pn[1] = dy; pn[2] = dz; pn[3] = len;
    }
    __syncthreads();

    // ---- first-layer fb_block means into sblk0 cols 8..31 ----
    if (tl < 112) {
        int e = tl / 8, k = tl % 8;
        float su_ = 0.f, sd_ = 0.f;
        for (int i = 0; i < 7; i++)  su_ += sb[i * 32 + k];
        for (int i = 7; i < 14; i++) sd_ += sb[i * 32 + k];
        sb[e * 32 + 8 + k]  = su_ * (1.f / 7.f);
        sb[e * 32 + 16 + k] = sd_ * (1.f / 7.f);
    }
    if (tl >= 128 && tl < 128 + 56) {
        int q = tl - 128; int j = q / 4, c = q % 4;
        float su_ = 0.f, sd_ = 0.f;
        for (int i = 0; i < 7; i++)  su_ += sb[448 + (i * N_E + j) * 4 + c];
        for (int i = 7; i < 14; i++) sd_ += sb[448 + (i * N_E + j) * 4 + c];
        sb[j * 32 + 24 + c] = su_ * (1.f / 7.f);
        sb[j * 32 + 28 + c] = sd_ * (1.f / 7.f);
    }
    __syncthreads();

    // ---- first s layer: sv = tanh(sblk0 @ s_w0 + s_b0) ----
    {
        const int n = tl;
        float acc[N_E];
        float bias = s_b0[n];
        #pragma unroll
        for (int e = 0; e < N_E; e++) acc[e] = bias;
        for (int k = 0; k < 32; k += 4) {
            float w0 = s_w0[(k + 0) * N_SV + n];
            float w1 = s_w0[(k + 1) * N_SV + n];
            float w2 = s_w0[(k + 2) * N_SV + n];
            float w3 = s_w0[(k + 3) * N_SV + n];
            #pragma unroll
            for (int e = 0; e < N_E; e++) {
                float4 s4 = *(const float4*)&sb[e * 32 + k];
                acc[e] += s4.x * w0 + s4.y * w1 + s4.z * w2 + s4.w * w3;
            }
        }
        #pragma unroll
        for (int e = 0; e < N_E; e++) svp[e * N_SV + n] = tanh_fast(acc[e]);
    }

    // ---- first p layer: pv = tanh(pin @ p_w0 + p_b0) ----
    {
        const int c = tl & 31, pr0 = tl >> 5;
        float w0 = p_w0[c], w1 = p_w0[32 + c], w2 = p_w0[64 + c], w3 = p_w0[96 + c];
        float bias = p_b0[c];
        #pragma unroll
        for (int m = 0; m < 25; m++) {
            int pair = pr0 + (m << 3);
            if (pair < N_PAIR) {
                float4 q4 = *(const float4*)&sb[448 + pair * 4];
                pvp[pair * N_PV + c] = tanh_fast(bias + q4.x * w0 + q4.y * w1 + q4.z * w2 + q4.w * w3);
            }
        }
    }
    __syncthreads();

    // ---- FB iterations (it<3: residual layers; it==3: final va layer) ----
    for (int it = 0; it <= N_FB; it++) {
        // s-means: thread n reads its own column
        {
            const int n = tl;
            float su_ = 0.f, sd_ = 0.f;
            #pragma unroll
            for (int e = 0; e < 7; e++)  su_ += svp[e * N_SV + n];
            #pragma unroll
            for (int e = 7; e < 14; e++) sd_ += svp[e * N_SV + n];
            mu[n] = su_ * (1.f / 7.f);
            md[n] = sd_ * (1.f / 7.f);
        }
        // p-means
        for (int idx = tl; idx < N_E * N_PV; idx += 256) {
            int j = idx >> 5, c = idx & 31;
            float su_ = 0.f, sd_ = 0.f;
            for (int i = 0; i < 7; i++)  su_ += pvp[(i * N_E + j) * N_PV + c];
            for (int i = 7; i < 14; i++) sd_ += pvp[(i * N_E + j) * N_PV + c];
            pu[j * N_PV + c] = su_ * (1.f / 7.f);
            pd[j * N_PV + c] = sd_ * (1.f / 7.f);
        }
        __syncthreads();

        const bool last = (it == N_FB);
        const float* W = last ? va_w : (s_w + it * 832 * N_SV);
        const float* B = last ? va_b : (s_b + it * N_SV);
        const int n = tl;

        // shared base: mu @ W[256:512] + md @ W[512:768] + bias
        float base = B[n];
        #pragma unroll 2
        for (int k = 0; k < N_SV; k += 4) {
            float4 m4 = *(const float4*)&mu[k];
            const float* Wk = W + (N_SV + k) * N_SV + n;
            base += m4.x * Wk[0] + m4.y * Wk[N_SV] + m4.z * Wk[2 * N_SV] + m4.w * Wk[3 * N_SV];
            float4 d4 = *(const float4*)&md[k];
            const float* Wk2 = W + (2 * N_SV + k) * N_SV + n;
            base += d4.x * Wk2[0] + d4.y * Wk2[N_SV] + d4.z * Wk2[2 * N_SV] + d4.w * Wk2[3 * N_SV];
        }

        float acc[N_E];
        #pragma unroll
        for (int e = 0; e < N_E; e++) acc[e] = base;

        // per-electron: sv @ W[0:256]
        #pragma unroll 2
        for (int k = 0; k < N_SV; k += 4) {
            const float* Wk = W + k * N_SV + n;
            float w0 = Wk[0], w1 = Wk[N_SV], w2 = Wk[2 * N_SV], w3 = Wk[3 * N_SV];
            #pragma unroll
            for (int e = 0; e < N_E; e++) {
                float4 s4 = *(const float4*)&svp[e * N_SV + k];
                acc[e] += s4.x * w0 + s4.y * w1 + s4.z * w2 + s4.w * w3;
            }
        }
        // per-electron: pu @ W[768:800], pd @ W[800:832]
        for (int k = 0; k < N_PV; k += 4) {
            const float* Wk = W + (3 * N_SV + k) * N_SV + n;
            float w0 = Wk[0], w1 = Wk[N_SV], w2 = Wk[2 * N_SV], w3 = Wk[3 * N_SV];
            #pragma unroll
            for (int e = 0; e < N_E; e++) {
                float4 q4 = *(const float4*)&pu[e * N_PV + k];
                acc[e] += q4.x * w0 + q4.y * w1 + q4.z * w2 + q4.w * w3;
            }
            const float* Wk2 = W + (3 * N_SV + N_PV + k) * N_SV + n;
            float v0 = Wk2[0], v1 = Wk2[N_SV], v2 = Wk2[2 * N_SV], v3 = Wk2[3 * N_SV];
            #pragma unroll
            for (int e = 0; e < N_E; e++) {
                float4 q4 = *(const float4*)&pd[e * N_PV + k];
                acc[e] += q4.x * v0 + q4.y * v1 + q4.z * v2 + q4.w * v3;
            }
        }

        #pragma unroll
        for (int e = 0; e < N_E; e++) {
            float th = tanh_fast(acc[e]);
            acc[e] = last ? th : (th + svp[e * N_SV + n]);
        }
        __syncthreads();
        #pragma unroll
        for (int e = 0; e < N_E; e++) svp[e * N_SV + n] = acc[e];
        __syncthreads();

        if (!last) {
            // p layer: pv = tanh(pv @ p_w[it] + p_b[it]) + pv, 2 chunks of 98 pairs
            const int c = tl & 31, pr0 = tl >> 5;
            float wreg[N_PV];
            #pragma unroll
            for (int k = 0; k < N_PV; k++) wreg[k] = p_w[it * N_PV * N_PV + k * N_PV + c];
            const float bias = p_b[it * N_PV + c];

            #pragma unroll
            for (int ch = 0; ch < 2; ch++) {
                const int pbase = ch * 98;
                float res[13];
                #pragma unroll
                for (int m = 0; m < 13; m++) {
                    int q = pr0 + (m << 3);
                    if (q < 98) {
                        int pair = pbase + q;
                        float a = bias;
                        #pragma unroll
                        for (int k = 0; k < N_PV; k += 4) {
                            float4 q4 = *(const float4*)&pvp[pair * N_PV + k];
                            a += q4.x * wreg[k] + q4.y * wreg[k + 1] + q4.z * wreg[k + 2] + q4.w * wreg[k + 3];
                        }
                        res[m] = tanh_fast(a) + pvp[pair * N_PV + c];
                    }
                }
                __syncthreads();
                #pragma unroll
                for (int m = 0; m < 13; m++) {
                    int q = pr0 + (m << 3);
                    if (q < 98) pvp[(pbase + q) * N_PV + c] = res[m];
                }
                __syncthreads();
            }
        }
    }

    // ---- orbitals: sw = sv @ w{u,d}_w + b, scaled by env, scattered to det matrices ----
    for (int idx = tl; idx < 2 * 784; idx += 256) {
        int sgrp = idx / 784;
        int rem  = idx % 784;
        int e    = rem / 112;
        int col  = rem % 112;
        const float* W  = sgrp ? wd_w : wu_w;
        const float* Bb = sgrp ? wd_b : wu_b;
        float a = Bb[col];
        const float* srow = svp + (sgrp * 7 + e) * N_SV;
        for (int k = 0; k < N_SV; k += 4) {
            float4 s4 = *(const float4*)&srow[k];
            a += s4.x * W[(k + 0) * 112 + col] + s4.y * W[(k + 1) * 112 + col]
               + s4.z * W[(k + 2) * 112 + col] + s4.w * W[(k + 3) * 112 + col];
        }
        int o = col / 16, d = col % 16;
        sb[(sgrp * 16 + d) * 49 + o * 7 + e] = a * env[sgrp * 7 + e];
    }
    __syncthreads();

    // ---- slogdet via LU with partial pivoting: one 7x7 det per thread ----
    if (tl < 32) {
        float* A = sb + tl * 49;
        float sg = 1.0f, ld = 0.0f;
        for (int c0 = 0; c0 < 7; c0++) {
            int p = c0; float mx = fabsf(A[c0 * 7 + c0]);
            for (int rI = c0 + 1; rI < 7; rI++) {
                float v = fabsf(A[rI * 7 + c0]);
                if (v > mx) { mx = v; p = rI; }
            }
            if (p != c0) {
                for (int c2 = 0; c2 < 7; c2++) {
                    float tmp = A[c0 * 7 + c2]; A[c0 * 7 + c2] = A[p * 7 + c2]; A[p * 7 + c2] = tmp;
                }
                sg = -sg;
            }
            float piv = A[c0 * 7 + c0];
            if (piv < 0.f) sg = -sg;
            ld += __logf(fabsf(piv));
            float rp = 1.0f / piv;
            for (int rI = c0 + 1; rI < 7; rI++) {
                float f = A[rI * 7 + c0] * rp;
                for (int c2 = c0 + 1; c2 < 7; c2++) A[rI * 7 + c2] -= f * A[c0 * 7 + c2];
            }
        }
        dsgp[tl] = sg; dldp[tl] = ld;
    }
    __syncthreads();

    // ---- combine ----
    if (tl == 0) {
        float mx = -1e30f;
        float ld[16], sg[16];
        #pragma unroll
        for (int d = 0; d < 16; d++) {
            ld[d] = dldp[d] + dldp[16 + d];
            sg[d] = dsgp[d] * dsgp[16 + d];
            mx = fmaxf(mx, ld[d]);
        }
        float psi = 0.f;
        #pragma unroll
        for (int d = 0; d < 16; d++) psi += sg[d] * __expf(ld[d] - mx) * wf_w[d];
        out[b2] = __logf(fabsf(psi)) + mx;
    }
}

extern "C" void kernel_launch(void* const* d_in, const int* in_sizes, int n_in,
                              void* d_out, int out_size, void* d_ws, size_t ws_size,
                              hipStream_t stream) {
    (void)n_in; (void)d_ws; (void)ws_size; (void)out_size;
    const float* r    = (const float*)d_in[0];
    const float* s_w0 = (const float*)d_in[1];
    const float* s_b0 = (const float*)d_in[2];
    const float* s_w  = (const float*)d_in[3];
    const float* s_b  = (const float*)d_in[4];
    const float* p_w0 = (const float*)d_in[5];
    const float* p_b0 = (const float*)d_in[6];
    const float* p_w  = (const float*)d_in[7];
    const float* p_b  = (const float*)d_in[8];
    const float* va_w = (const float*)d_in[9];
    const float* va_b = (const float*)d_in[10];
    const float* wu_w = (const float*)d_in[11];
    const float* wu_b = (const float*)d_in[12];
    const float* wd_w = (const float*)d_in[13];
    const float* wd_b = (const float*)d_in[14];
    const float* wf_w = (const float*)d_in[15];
    float* out = (float*)d_out;

    // allow >64 KB dynamic LDS (idempotent; host-side, graph-capture-safe)
    hipFuncSetAttribute((const void*)ansatz_kernel,
                        hipFuncAttributeMaxDynamicSharedMemorySize, LDS_BYTES);

    const int nb = in_sizes[0] / (N_E * 3);
    hipLaunchKernelGGL(ansatz_kernel, dim3(nb / 2), dim3(512), LDS_BYTES, stream,
                       r, s_w0, s_b0, s_w, s_b, p_w0, p_b0, p_w, p_b,
                       va_w, va_b, wu_w, wu_b, wd_w, wd_b, wf_w, out);
}